// Round 2
// baseline (2166.454 us; speedup 1.0000x reference)
//
#include <hip/hip_runtime.h>

// LSTMBaseline: B=2048, T=512, H=128, 4H=512, FF=64, OUT=2 ; fp32 in/out.
// R11: spill post-mortem — 192 regs of weight frags + ~120 arch > 256/wave
// budget (8 waves/CU). 384KB block weights = 75% of the 512KB/CU reg file:
// full residency is impossible; compiler scratch (33MB device-wide, HBM-
// missing) was the streaming channel. Fixes:
//  (1) whh1 (64 regs) streamed from a frag-ordered, pre-scaled bf16 table in
//      d_ws (prep kernel): shared 128KB, L2-resident, 1KB-coalesced reads,
//      prefetched 2 groups deep under MFMA cover. AGPR weights: 128.
//  (2) gbuf handoff ELIMINATED: MFMA C-layout (col=lane&15, row=4*kg+rr)
//      means lanes kg<2 hold all 8 real batch rows for their column -> cell
//      math runs divergent on 32 lanes straight from the accumulator.
//      Saves ~48 LDS ops/wave/step.
//  (3) single reused acc (cell0 between MM0 and MM1); a0 re-read per pass;
//      arch VGPR peak ~120 -> 128 arch + 128 AGPR = 256, zero spill.
//  (4) biases folded into acc init; weights pre-scaled by log2e (2*log2e for
//      g-gate); inputs staged as float2 xin[8][514] (rows 4 banks apart).

#define TT 512
#define HH 128
#define FFD 64
#define BB 8
#define NT 512   // threads per block = 8 waves
#define HP 136   // padded LDS row stride (ushort); 272B = 16B-aligned rows
#define XP (TT + 2)  // float2 row stride: 4112B -> consecutive rows 4 banks apart

typedef __attribute__((ext_vector_type(8))) short short8;
typedef __attribute__((ext_vector_type(4))) float f32x4;

#define L2E  1.4426950408889634f
#define L2E2 2.8853900817779268f

__device__ __forceinline__ unsigned short f2b(float f) {
    unsigned int i = __builtin_bit_cast(unsigned int, f);
    i += 0x7FFFu + ((i >> 16) & 1u);   // RNE
    return (unsigned short)(i >> 16);
}
__device__ __forceinline__ float b2f(unsigned short u) {
    return __builtin_bit_cast(float, ((unsigned int)u) << 16);
}
__device__ __forceinline__ float fexp2(float x) {
#if __has_builtin(__builtin_amdgcn_exp2f)
    return __builtin_amdgcn_exp2f(x);     // v_exp_f32
#else
    return exp2f(x);
#endif
}
__device__ __forceinline__ float frcp(float x) {
#if __has_builtin(__builtin_amdgcn_rcpf)
    return __builtin_amdgcn_rcpf(x);      // v_rcp_f32
#else
    return 1.0f / x;
#endif
}
// pre-scaled activations: y already multiplied by log2e (sigm) / 2*log2e (tanh)
__device__ __forceinline__ float sigm_s(float y) {
    return frcp(1.0f + fexp2(-y));
}
__device__ __forceinline__ float tanh_s(float y) {
    return 1.0f - 2.0f * frcp(1.0f + fexp2(y));
}
// natural-domain tanh (for cell state c)
__device__ __forceinline__ float tanh_c(float x) {
    return 1.0f - 2.0f * frcp(1.0f + fexp2(L2E2 * x));
}
// 8 consecutive fp32 -> bf16 short8 fragment, scaled
__device__ __forceinline__ short8 ldfrag(const float* p, unsigned idx, float s) {
    const float4* q = reinterpret_cast<const float4*>(p + idx);
    float4 a = q[0], b = q[1];
    short8 r;
    r[0] = (short)f2b(a.x * s); r[1] = (short)f2b(a.y * s);
    r[2] = (short)f2b(a.z * s); r[3] = (short)f2b(a.w * s);
    r[4] = (short)f2b(b.x * s); r[5] = (short)f2b(b.y * s);
    r[6] = (short)f2b(b.z * s); r[7] = (short)f2b(b.w * s);
    return r;
}

// ---- prep: whh1 fp32 -> pre-scaled bf16 MFMA B-frags, frag-ordered in ws.
// Layout: wsf[(kt*4+g)*NT + tid] so one wave-instruction reads contiguous 1KB.
__global__ void prep_whh1(const float* __restrict__ whh1, short8* __restrict__ wsf) {
    const int tid  = threadIdx.x;            // 0..511
    const int bidx = blockIdx.x;             // 0..15 = kt*4+g
    const int lane = tid & 63;
    const int wv   = tid >> 6;
    const int nrow = lane & 15;
    const int kg   = lane >> 4;
    const int kt   = bidx >> 2;
    const int g    = bidx & 3;
    const float s  = (g == 2) ? L2E2 : L2E;
    unsigned gc = (unsigned)(128 * g + 16 * wv + nrow);
    wsf[(unsigned)bidx * NT + tid] = ldfrag(whh1, gc * HH + kt * 32 + kg * 8, s);
}

__global__ __launch_bounds__(NT, 2) void lstm2_fused(
    const float* __restrict__ hr,
    const float* __restrict__ glu,
    const float* __restrict__ wih0,
    const float* __restrict__ whh0,
    const float* __restrict__ bih0,
    const float* __restrict__ bhh0,
    const float* __restrict__ wih1,
    const float* __restrict__ bih1,
    const float* __restrict__ bhh1,
    const float* __restrict__ w1,
    const float* __restrict__ b1,
    const float* __restrict__ w2,
    const float* __restrict__ b2,
    const short8* __restrict__ wsf,
    float* __restrict__ out)
{
    // h(t) lives in buffer t&1. Rows 8..15 stay zero (MFMA M=16 padding).
    __shared__ __align__(16) unsigned short h0b[2][16][HP];
    __shared__ __align__(16) unsigned short h1b[2][16][HP];
    __shared__ __align__(16) float2 xin[BB][XP];
    __shared__ float hid[BB][FFD];

    const int tid  = threadIdx.x;
    const int lane = tid & 63;
    const int wv   = tid >> 6;        // 0..7
    const int nrow = lane & 15;       // MFMA m (A) / n (B) index
    const int kg   = lane >> 4;       // MFMA k-group 0..3
    const int b0   = blockIdx.x * BB;

    // ---- init LDS ----
    {
        unsigned short* p0 = &h0b[0][0][0];
        unsigned short* p1 = &h1b[0][0][0];
        for (int i = tid; i < 2 * 16 * HP; i += NT) { p0[i] = 0; p1[i] = 0; }
        for (int i = tid; i < BB * TT; i += NT) {   // coalesced over t
            int row = i >> 9;
            int t   = i & (TT - 1);
            unsigned gi = (unsigned)(b0 + row) * TT + t;
            float2 v; v.x = hr[gi]; v.y = glu[gi];
            xin[row][t] = v;
        }
    }

    // ---- resident weight frags: whh0 + wih1 = 32 frags = 128 AGPR ----
    // B-frag 16x16x32: lane(n=lane&15, q=lane>>4) holds B[k=32kt+8q+e][n]=W[col][k]
    short8 W0f[4][4];   // [g][kt] whh0
    short8 Wi1[4][4];   // [g][kt] wih1
#pragma unroll
    for (int g = 0; g < 4; g++) {
        const float s = (g == 2) ? L2E2 : L2E;
        unsigned gc = (unsigned)(128 * g + 16 * wv + nrow);
#pragma unroll
        for (int kt = 0; kt < 4; kt++) {
            unsigned off = gc * HH + kt * 32 + kg * 8;
            W0f[g][kt] = ldfrag(whh0, off, s);
            Wi1[g][kt] = ldfrag(wih1, off, s);
        }
    }
#pragma unroll
    for (int g = 0; g < 4; g++)
#pragma unroll
        for (int kt = 0; kt < 4; kt++) {
            asm volatile("" : "+a"(W0f[g][kt]));
            asm volatile("" : "+a"(Wi1[g][kt]));
        }

    // ---- per-lane constants (col = 128g + 16wv + nrow), pre-scaled ----
    float b0c[4], b1c[4], wax[4], wbx[4];
#pragma unroll
    for (int g = 0; g < 4; g++) {
        int col = 128 * g + 16 * wv + nrow;
        const float s = (g == 2) ? L2E2 : L2E;
        b0c[g] = (bih0[col] + bhh0[col]) * s;
        b1c[g] = (bih1[col] + bhh1[col]) * s;
        wax[g] = wih0[2 * col] * s;
        wbx[g] = wih0[2 * col + 1] * s;
    }

    const int j = 16 * wv + nrow;     // this lane's cell column (kg<2 lanes)
    float c0[4] = {0.f, 0.f, 0.f, 0.f};
    float c1[4] = {0.f, 0.f, 0.f, 0.f};
    __syncthreads();

    // ---- recurrence: ONE barrier per iteration ----
    for (int it = 0; it <= TT; it++) {
        const int p = (it + 1) & 1;   // buffer holding h(it-1)
        const int q = it & 1;         // buffer for h0(it); holds h1(it-2)
        const bool doA = (it < TT);
        const bool doB = (it > 0);

        // prefetch whh1 stream groups 0,1 (consumed in MM1-part2; ~MM0+cell0
        // of latency cover; 2 groups = 32 VGPR in flight)
        short8 wf[4][4];
        if (doB) {
#pragma unroll
            for (int kt = 0; kt < 2; kt++)
#pragma unroll
                for (int g = 0; g < 4; g++)
                    wf[kt][g] = wsf[(unsigned)(kt * 4 + g) * NT + tid];
        }

        f32x4 acc[4];
        if (doA) {
            // MM0(it): gates0 = bias0 + h0(it-1) @ whh0^T
#pragma unroll
            for (int g = 0; g < 4; g++) { float b = b0c[g]; f32x4 z = {b, b, b, b}; acc[g] = z; }
#pragma unroll
            for (int kt = 0; kt < 4; kt++) {
                short8 a0 = *reinterpret_cast<const short8*>(&h0b[p][nrow][kt * 32 + kg * 8]);
#pragma unroll
                for (int g = 0; g < 4; g++)
                    acc[g] = __builtin_amdgcn_mfma_f32_16x16x32_bf16(a0, W0f[g][kt], acc[g], 0, 0, 0);
            }
            // cell0(it): lanes kg<2 hold rows 4kg+rr of their column directly
            if (kg < 2) {
                float2 xv[4];
#pragma unroll
                for (int rr = 0; rr < 4; rr++) xv[rr] = xin[4 * kg + rr][it];
#pragma unroll
                for (int rr = 0; rr < 4; rr++) {
                    float pi = acc[0][rr] + xv[rr].x * wax[0] + xv[rr].y * wbx[0];
                    float pf = acc[1][rr] + xv[rr].x * wax[1] + xv[rr].y * wbx[1];
                    float pg = acc[2][rr] + xv[rr].x * wax[2] + xv[rr].y * wbx[2];
                    float po = acc[3][rr] + xv[rr].x * wax[3] + xv[rr].y * wbx[3];
                    float ig = sigm_s(pi), fg = sigm_s(pf), gg = tanh_s(pg), og = sigm_s(po);
                    float c = fg * c0[rr] + ig * gg;
                    c0[rr] = c;
                    h0b[q][4 * kg + rr][j] = f2b(og * tanh_c(c));   // h0(it) -> buf q
                }
            }
        }
        if (doB) {
            // MM1(it-1): gates1 = bias1 + h0(it-1) @ wih1^T + h1(it-2) @ whh1^T
#pragma unroll
            for (int g = 0; g < 4; g++) { float b = b1c[g]; f32x4 z = {b, b, b, b}; acc[g] = z; }
#pragma unroll
            for (int kt = 0; kt < 4; kt++) {
                short8 a0 = *reinterpret_cast<const short8*>(&h0b[p][nrow][kt * 32 + kg * 8]);
#pragma unroll
                for (int g = 0; g < 4; g++)
                    acc[g] = __builtin_amdgcn_mfma_f32_16x16x32_bf16(a0, Wi1[g][kt], acc[g], 0, 0, 0);
            }
#pragma unroll
            for (int kt = 0; kt < 4; kt++) {
                if (kt < 2) {   // prefetch group kt+2
#pragma unroll
                    for (int g = 0; g < 4; g++)
                        wf[kt + 2][g] = wsf[(unsigned)((kt + 2) * 4 + g) * NT + tid];
                }
                short8 a1 = *reinterpret_cast<const short8*>(&h1b[q][nrow][kt * 32 + kg * 8]);
#pragma unroll
                for (int g = 0; g < 4; g++)
                    acc[g] = __builtin_amdgcn_mfma_f32_16x16x32_bf16(a1, wf[kt][g], acc[g], 0, 0, 0);
            }
            // cell1(it-1): pre-activation complete (bias folded); h1 -> buf p
            if (kg < 2) {
#pragma unroll
                for (int rr = 0; rr < 4; rr++) {
                    float pi = acc[0][rr], pf = acc[1][rr], pg = acc[2][rr], po = acc[3][rr];
                    float ig = sigm_s(pi), fg = sigm_s(pf), gg = tanh_s(pg), og = sigm_s(po);
                    float c = fg * c1[rr] + ig * gg;
                    c1[rr] = c;
                    h1b[p][4 * kg + rr][j] = f2b(og * tanh_c(c));
                }
            }
        }
        __syncthreads();
    }

    // ---- head: h1 final = h1(TT-1) in h1b[(TT+1)&1] = h1b[1] ----
    {
        int r  = tid >> 6;      // 0..7
        int ff = tid & 63;
        float a2 = 0.f;
        for (int k = 0; k < HH; k++)
            a2 += b2f(h1b[1][r][k]) * w1[(unsigned)ff * HH + k];
        hid[r][ff] = fmaxf(a2 + b1[ff], 0.f);
    }
    __syncthreads();
    if (tid < 16) {
        int r = tid >> 1;
        int o = tid & 1;
        float a2 = b2[o];
        for (int k = 0; k < FFD; k++)
            a2 += hid[r][k] * w2[(unsigned)o * FFD + k];
        out[(b0 + r) * 2 + o] = a2;    // fp32 output
    }
}

extern "C" void kernel_launch(void* const* d_in, const int* in_sizes, int n_in,
                              void* d_out, int out_size, void* d_ws, size_t ws_size,
                              hipStream_t stream) {
    const float* hr   = (const float*)d_in[0];
    const float* glu  = (const float*)d_in[1];
    const float* wih0 = (const float*)d_in[2];
    const float* whh0 = (const float*)d_in[3];
    const float* bih0 = (const float*)d_in[4];
    const float* bhh0 = (const float*)d_in[5];
    const float* wih1 = (const float*)d_in[6];
    const float* whh1 = (const float*)d_in[7];
    const float* bih1 = (const float*)d_in[8];
    const float* bhh1 = (const float*)d_in[9];
    const float* w1   = (const float*)d_in[10];
    const float* b1   = (const float*)d_in[11];
    const float* w2   = (const float*)d_in[12];
    const float* b2   = (const float*)d_in[13];
    float* out = (float*)d_out;
    short8* wsf = (short8*)d_ws;      // 16 frag-sets * 512 thr * 16B = 128KB

    prep_whh1<<<dim3(16), dim3(NT), 0, stream>>>(whh1, wsf);
    lstm2_fused<<<dim3(2048 / BB), dim3(NT), 0, stream>>>(
        hr, glu, wih0, whh0, bih0, bhh0, wih1, bih1, bhh1,
        w1, b1, w2, b2, wsf, out);
}

// Round 3
// 1299.244 us; speedup vs baseline: 1.6675x; 1.6675x over previous
//
#include <hip/hip_runtime.h>

// LSTMBaseline: B=2048, T=512, H=128, 4H=512, FF=64, OUT=2 ; fp32 in/out.
// R12: register-file arithmetic: 8-wave block => <=256 regs/wave; 3 weight
// matrices = 192 frag-regs + ~120 arch > 256 => ONE matrix must stream.
// R11 proved global-L2 streaming stalls (vmcnt cliffs, MfmaUtil 15%).
// This round streams whh1 from a 128KB frag-ordered LDS table instead:
//  (1) wtab[16][512] short8 in LDS, filled ONCE at init from global whh1
//      (pre-scaled bf16). Per-step reads are lane-linear ds_read_b128
//      (conflict-free), prefetched one kt-group (~16 MFMAs) ahead.
//  (2) AGPR residency = whh0 + wih1 = 128 regs exactly (proven allocatable);
//      arch budget 128, est. peak ~116 => zero spill (watch WRITE_SIZE).
//  (3) xin LDS staging dropped: inputs read directly from global (broadcast
//      within 16-lane groups, L1-resident 32KB/CU), prefetched at iter top.
//  (4) a0 frags kept in regs across MM0->MM1 (saves 4 b128 reads/wave/step).
//  (5) biases folded into acc init; weights pre-scaled by log2e (2*log2e for
//      g-gate) so sigm/tanh lose their leading multiply.
// LDS total: 131072 + 2*8704 + 2048 = 150528 B < 160 KiB.

#define TT 512
#define HH 128
#define FFD 64
#define BB 8
#define NT 512   // threads per block = 8 waves
#define HP 136   // padded LDS row stride (ushort); 272B = 16B-aligned rows

typedef __attribute__((ext_vector_type(8))) short short8;
typedef __attribute__((ext_vector_type(4))) float f32x4;

#define L2E  1.4426950408889634f
#define L2E2 2.8853900817779268f

__device__ __forceinline__ unsigned short f2b(float f) {
    unsigned int i = __builtin_bit_cast(unsigned int, f);
    i += 0x7FFFu + ((i >> 16) & 1u);   // RNE
    return (unsigned short)(i >> 16);
}
__device__ __forceinline__ float b2f(unsigned short u) {
    return __builtin_bit_cast(float, ((unsigned int)u) << 16);
}
__device__ __forceinline__ float fexp2(float x) {
#if __has_builtin(__builtin_amdgcn_exp2f)
    return __builtin_amdgcn_exp2f(x);     // v_exp_f32
#else
    return exp2f(x);
#endif
}
__device__ __forceinline__ float frcp(float x) {
#if __has_builtin(__builtin_amdgcn_rcpf)
    return __builtin_amdgcn_rcpf(x);      // v_rcp_f32
#else
    return 1.0f / x;
#endif
}
// pre-scaled activations: y already multiplied by log2e (sigm) / 2*log2e (tanh)
__device__ __forceinline__ float sigm_s(float y) {
    return frcp(1.0f + fexp2(-y));
}
__device__ __forceinline__ float tanh_s(float y) {
    return 1.0f - 2.0f * frcp(1.0f + fexp2(y));
}
// natural-domain tanh (for cell state c)
__device__ __forceinline__ float tanh_c(float x) {
    return 1.0f - 2.0f * frcp(1.0f + fexp2(L2E2 * x));
}
// 8 consecutive fp32 -> bf16 short8 fragment, scaled
__device__ __forceinline__ short8 ldfrag(const float* p, unsigned idx, float s) {
    const float4* q = reinterpret_cast<const float4*>(p + idx);
    float4 a = q[0], b = q[1];
    short8 r;
    r[0] = (short)f2b(a.x * s); r[1] = (short)f2b(a.y * s);
    r[2] = (short)f2b(a.z * s); r[3] = (short)f2b(a.w * s);
    r[4] = (short)f2b(b.x * s); r[5] = (short)f2b(b.y * s);
    r[6] = (short)f2b(b.z * s); r[7] = (short)f2b(b.w * s);
    return r;
}

#define MFMA(a, b, c) __builtin_amdgcn_mfma_f32_16x16x32_bf16((a), (b), (c), 0, 0, 0)

__global__ __launch_bounds__(NT, 2) void lstm2_fused(
    const float* __restrict__ hr,
    const float* __restrict__ glu,
    const float* __restrict__ wih0,
    const float* __restrict__ whh0,
    const float* __restrict__ bih0,
    const float* __restrict__ bhh0,
    const float* __restrict__ wih1,
    const float* __restrict__ whh1,
    const float* __restrict__ bih1,
    const float* __restrict__ bhh1,
    const float* __restrict__ w1,
    const float* __restrict__ b1,
    const float* __restrict__ w2,
    const float* __restrict__ b2,
    float* __restrict__ out)
{
    // h(t) lives in buffer t&1. Rows 8..15 stay zero (MFMA M=16 padding).
    __shared__ __align__(16) unsigned short h0b[2][16][HP];
    __shared__ __align__(16) unsigned short h1b[2][16][HP];
    __shared__ __align__(16) short8 wtab[16][NT];   // whh1 frags [(kt*4+g)][tid]
    __shared__ float hid[BB][FFD];

    const int tid  = threadIdx.x;
    const int lane = tid & 63;
    const int wv   = tid >> 6;        // 0..7
    const int nrow = lane & 15;       // MFMA m (A) / n (B) index
    const int kg   = lane >> 4;       // MFMA k-group 0..3
    const int b0   = blockIdx.x * BB;

    // ---- init h buffers ----
    {
        unsigned short* p0 = &h0b[0][0][0];
        unsigned short* p1 = &h1b[0][0][0];
        for (int i = tid; i < 2 * 16 * HP; i += NT) { p0[i] = 0; p1[i] = 0; }
    }

    // ---- wtab: whh1 -> pre-scaled bf16 frags, resident in LDS ----
    // B-frag 16x16x32: lane(n=lane&15, q=lane>>4) holds B[k=32kt+8q+e][n]=W[col][k]
#pragma unroll
    for (int g = 0; g < 4; g++) {
        const float s = (g == 2) ? L2E2 : L2E;
        unsigned gc = (unsigned)(128 * g + 16 * wv + nrow);
#pragma unroll
        for (int kt = 0; kt < 4; kt++)
            wtab[kt * 4 + g][tid] = ldfrag(whh1, gc * HH + kt * 32 + kg * 8, s);
    }

    // ---- resident AGPR frags: whh0 + wih1 = 32 frags = 128 regs ----
    short8 W0f[4][4];   // [g][kt] whh0
    short8 Wi1[4][4];   // [g][kt] wih1
#pragma unroll
    for (int g = 0; g < 4; g++) {
        const float s = (g == 2) ? L2E2 : L2E;
        unsigned gc = (unsigned)(128 * g + 16 * wv + nrow);
#pragma unroll
        for (int kt = 0; kt < 4; kt++) {
            unsigned off = gc * HH + kt * 32 + kg * 8;
            W0f[g][kt] = ldfrag(whh0, off, s);
            Wi1[g][kt] = ldfrag(wih1, off, s);
        }
    }
#pragma unroll
    for (int g = 0; g < 4; g++)
#pragma unroll
        for (int kt = 0; kt < 4; kt++) {
            asm volatile("" : "+a"(W0f[g][kt]));
            asm volatile("" : "+a"(Wi1[g][kt]));
        }

    // ---- per-lane constants (col = 128g + 16wv + nrow), pre-scaled ----
    float b0c[4], b1c[4], wax[4], wbx[4];
#pragma unroll
    for (int g = 0; g < 4; g++) {
        int col = 128 * g + 16 * wv + nrow;
        const float s = (g == 2) ? L2E2 : L2E;
        b0c[g] = (bih0[col] + bhh0[col]) * s;
        b1c[g] = (bih1[col] + bhh1[col]) * s;
        wax[g] = wih0[2 * col] * s;
        wbx[g] = wih0[2 * col + 1] * s;
    }

    const int j = 16 * wv + nrow;     // this lane's cell column (kg<2 lanes)
    float c0[4] = {0.f, 0.f, 0.f, 0.f};
    float c1[4] = {0.f, 0.f, 0.f, 0.f};
    __syncthreads();

    // ---- recurrence: ONE barrier per iteration ----
    for (int it = 0; it <= TT; it++) {
        const int p = (it + 1) & 1;   // buffer holding h0(it-1)
        const int q = it & 1;         // buffer for h0(it); holds h1(it-2)
        const bool doA = (it < TT);
        const bool doB = (it > 0);

        // x prefetch for cell0 (kg<2 lanes own rows 4kg+rr). Issued at iter
        // top; consumed after MM0 (~20 MFMA of latency cover). L1-resident.
        float xh[4], xg[4];
        if (doA && kg < 2) {
            const float* hp_ = hr  + (unsigned)(b0 + 4 * kg) * TT + it;
            const float* gp_ = glu + (unsigned)(b0 + 4 * kg) * TT + it;
#pragma unroll
            for (int rr = 0; rr < 4; rr++) {
                xh[rr] = hp_[(unsigned)rr * TT];
                xg[rr] = gp_[(unsigned)rr * TT];
            }
        }

        // A-frags of h0(it-1) — shared by MM0 and MM1 (kept in regs)
        short8 a0[4];
#pragma unroll
        for (int kt = 0; kt < 4; kt++)
            a0[kt] = *reinterpret_cast<const short8*>(&h0b[p][nrow][kt * 32 + kg * 8]);

        if (doA) {
            // MM0(it): gates0 = bias0 + h0(it-1) @ whh0^T
            f32x4 acc[4];
#pragma unroll
            for (int g = 0; g < 4; g++) { float b = b0c[g]; f32x4 z = {b, b, b, b}; acc[g] = z; }
#pragma unroll
            for (int kt = 0; kt < 4; kt++)
#pragma unroll
                for (int g = 0; g < 4; g++)
                    acc[g] = MFMA(a0[kt], W0f[g][kt], acc[g]);
            // cell0(it): lanes kg<2 hold rows 4kg+rr of their column directly
            if (kg < 2) {
#pragma unroll
                for (int rr = 0; rr < 4; rr++) {
                    float pi = acc[0][rr] + xh[rr] * wax[0] + xg[rr] * wbx[0];
                    float pf = acc[1][rr] + xh[rr] * wax[1] + xg[rr] * wbx[1];
                    float pg = acc[2][rr] + xh[rr] * wax[2] + xg[rr] * wbx[2];
                    float po = acc[3][rr] + xh[rr] * wax[3] + xg[rr] * wbx[3];
                    float ig = sigm_s(pi), fg = sigm_s(pf), gg = tanh_s(pg), og = sigm_s(po);
                    float c = fg * c0[rr] + ig * gg;
                    c0[rr] = c;
                    h0b[q][4 * kg + rr][j] = f2b(og * tanh_c(c));   // h0(it) -> buf q
                }
            }
        }
        if (doB) {
            // MM1(it-1): gates1 = bias1 + h0(it-1)@wih1^T + h1(it-2)@whh1^T
            f32x4 acc[4];
            short8 wf0[4], wf1[4];
            // prefetch whh1 kt-group 0 (covered by the 16 Wi1 MFMAs below)
#pragma unroll
            for (int g = 0; g < 4; g++) wf0[g] = wtab[g][tid];
#pragma unroll
            for (int g = 0; g < 4; g++) { float b = b1c[g]; f32x4 z = {b, b, b, b}; acc[g] = z; }
            // part1: h0 @ wih1^T (AGPR weights)
#pragma unroll
            for (int kt = 0; kt < 4; kt++)
#pragma unroll
                for (int g = 0; g < 4; g++)
                    acc[g] = MFMA(a0[kt], Wi1[g][kt], acc[g]);
            // part2: h1 @ whh1^T, whh1 streamed from LDS, 1-group prefetch.
            {
                short8 a1;
                a1 = *reinterpret_cast<const short8*>(&h1b[q][nrow][0 * 32 + kg * 8]);
#pragma unroll
                for (int g = 0; g < 4; g++) wf1[g] = wtab[4 + g][tid];
#pragma unroll
                for (int g = 0; g < 4; g++) acc[g] = MFMA(a1, wf0[g], acc[g]);

                a1 = *reinterpret_cast<const short8*>(&h1b[q][nrow][1 * 32 + kg * 8]);
#pragma unroll
                for (int g = 0; g < 4; g++) wf0[g] = wtab[8 + g][tid];
#pragma unroll
                for (int g = 0; g < 4; g++) acc[g] = MFMA(a1, wf1[g], acc[g]);

                a1 = *reinterpret_cast<const short8*>(&h1b[q][nrow][2 * 32 + kg * 8]);
#pragma unroll
                for (int g = 0; g < 4; g++) wf1[g] = wtab[12 + g][tid];
#pragma unroll
                for (int g = 0; g < 4; g++) acc[g] = MFMA(a1, wf0[g], acc[g]);

                a1 = *reinterpret_cast<const short8*>(&h1b[q][nrow][3 * 32 + kg * 8]);
#pragma unroll
                for (int g = 0; g < 4; g++) acc[g] = MFMA(a1, wf1[g], acc[g]);
            }
            // cell1(it-1): pre-activation complete (bias folded); h1 -> buf p
            if (kg < 2) {
#pragma unroll
                for (int rr = 0; rr < 4; rr++) {
                    float pi = acc[0][rr], pf = acc[1][rr], pg = acc[2][rr], po = acc[3][rr];
                    float ig = sigm_s(pi), fg = sigm_s(pf), gg = tanh_s(pg), og = sigm_s(po);
                    float c = fg * c1[rr] + ig * gg;
                    c1[rr] = c;
                    h1b[p][4 * kg + rr][j] = f2b(og * tanh_c(c));
                }
            }
        }
        __syncthreads();
    }

    // ---- head: h1 final = h1(TT-1) in h1b[(TT+1)&1] = h1b[1] ----
    {
        int r  = tid >> 6;      // 0..7
        int ff = tid & 63;
        float a2 = 0.f;
        for (int k = 0; k < HH; k++)
            a2 += b2f(h1b[1][r][k]) * w1[(unsigned)ff * HH + k];
        hid[r][ff] = fmaxf(a2 + b1[ff], 0.f);
    }
    __syncthreads();
    if (tid < 16) {
        int r = tid >> 1;
        int o = tid & 1;
        float a2 = b2[o];
        for (int k = 0; k < FFD; k++)
            a2 += hid[r][k] * w2[(unsigned)o * FFD + k];
        out[(b0 + r) * 2 + o] = a2;    // fp32 output
    }
}

extern "C" void kernel_launch(void* const* d_in, const int* in_sizes, int n_in,
                              void* d_out, int out_size, void* d_ws, size_t ws_size,
                              hipStream_t stream) {
    const float* hr   = (const float*)d_in[0];
    const float* glu  = (const float*)d_in[1];
    const float* wih0 = (const float*)d_in[2];
    const float* whh0 = (const float*)d_in[3];
    const float* bih0 = (const float*)d_in[4];
    const float* bhh0 = (const float*)d_in[5];
    const float* wih1 = (const float*)d_in[6];
    const float* whh1 = (const float*)d_in[7];
    const float* bih1 = (const float*)d_in[8];
    const float* bhh1 = (const float*)d_in[9];
    const float* w1   = (const float*)d_in[10];
    const float* b1   = (const float*)d_in[11];
    const float* w2   = (const float*)d_in[12];
    const float* b2   = (const float*)d_in[13];
    float* out = (float*)d_out;

    lstm2_fused<<<dim3(2048 / BB), dim3(NT), 0, stream>>>(
        hr, glu, wih0, whh0, bih0, bhh0, wih1, whh1, bih1, bhh1,
        w1, b1, w2, b2, out);
}

// Round 5
// 1251.077 us; speedup vs baseline: 1.7317x; 1.0385x over previous
//
#include <hip/hip_runtime.h>

// LSTMBaseline: B=2048, T=512, H=128, 4H=512, FF=64, OUT=2 ; fp32 in/out.
// R14 = R13 (4 waves x 512 regs, ALL weights AGPR-resident, no streaming)
// with the correctness bug fixed. R13's LDS "bounce" (write gb[kg], read
// gb[kg^2]) is compiler-reorderable: per-lane alias analysis PROVES the read
// address != write address (kg^2 != kg), so it may reorder them; the
// cross-lane dependency (lane L reads lane L^32's slot) is invisible.
// Result was stale gate values for rows {2,3,6,7} -> absmax 2.9e-3 (>thr).
// Fix: exchange acc[t][2..3] via __shfl(val, lane^32) — value flows through
// the intrinsic's SSA result, ordering enforced by data dependence. gb gone.
// Design recap:
//  (1) 4 waves/block, 512 regs/wave (occupancy quantum 1 wave/SIMD): 96
//      weight frags = 384 AGPR resident + ~110 arch VGPR. Zero streaming.
//  (2) wave owns 32 h-cols x 4 gates x both layers: 96 MFMA/wave/step,
//      8 independent acc chains.
//  (3) cell on ALL 64 lanes (2 rows x 2 cols per lane per layer); rows
//      {2,3,6,7} gate values arrive via __shfl from partner lane (lane^32).
//      Row map: kg0:{0,1} kg1:{4,5} kg2:{2,3} kg3:{6,7}.
//  (4) biases folded into MFMA acc init; weights pre-scaled by log2e (2x for
//      g-gate); cell consts in small LDS tables (b128 reads).
// LDS 27648 B. Watch WRITE_SIZE: >>2MB means 512-reg overflow (in-loop spill).

#define TT 512
#define HH 128
#define FFD 64
#define BB 8
#define NT 256   // 4 waves
#define HP 136   // padded LDS row stride (ushort); 272B = 16B-aligned rows

typedef __attribute__((ext_vector_type(8))) short short8;
typedef __attribute__((ext_vector_type(4))) float f32x4;

#define L2E  1.4426950408889634f
#define L2E2 2.8853900817779268f

__device__ __forceinline__ unsigned short f2b(float f) {
    unsigned int i = __builtin_bit_cast(unsigned int, f);
    i += 0x7FFFu + ((i >> 16) & 1u);   // RNE
    return (unsigned short)(i >> 16);
}
__device__ __forceinline__ float b2f(unsigned short u) {
    return __builtin_bit_cast(float, ((unsigned int)u) << 16);
}
__device__ __forceinline__ float fexp2(float x) {
#if __has_builtin(__builtin_amdgcn_exp2f)
    return __builtin_amdgcn_exp2f(x);     // v_exp_f32
#else
    return exp2f(x);
#endif
}
__device__ __forceinline__ float frcp(float x) {
#if __has_builtin(__builtin_amdgcn_rcpf)
    return __builtin_amdgcn_rcpf(x);      // v_rcp_f32
#else
    return 1.0f / x;
#endif
}
// pre-scaled activations: y already multiplied by log2e (sigm) / 2*log2e (tanh)
__device__ __forceinline__ float sigm_s(float y) {
    return frcp(1.0f + fexp2(-y));
}
__device__ __forceinline__ float tanh_s(float y) {
    return 1.0f - 2.0f * frcp(1.0f + fexp2(y));
}
// natural-domain tanh (for cell state c)
__device__ __forceinline__ float tanh_c(float x) {
    return 1.0f - 2.0f * frcp(1.0f + fexp2(L2E2 * x));
}
// 8 consecutive fp32 -> bf16 short8 fragment, scaled
__device__ __forceinline__ short8 ldfrag(const float* p, unsigned idx, float s) {
    const float4* q = reinterpret_cast<const float4*>(p + idx);
    float4 a = q[0], b = q[1];
    short8 r;
    r[0] = (short)f2b(a.x * s); r[1] = (short)f2b(a.y * s);
    r[2] = (short)f2b(a.z * s); r[3] = (short)f2b(a.w * s);
    r[4] = (short)f2b(b.x * s); r[5] = (short)f2b(b.y * s);
    r[6] = (short)f2b(b.z * s); r[7] = (short)f2b(b.w * s);
    return r;
}

#define MFMA(a, b, c) __builtin_amdgcn_mfma_f32_16x16x32_bf16((a), (b), (c), 0, 0, 0)

__global__ __launch_bounds__(NT, 1) void lstm2_fused(
    const float* __restrict__ hr,
    const float* __restrict__ glu,
    const float* __restrict__ wih0,
    const float* __restrict__ whh0,
    const float* __restrict__ bih0,
    const float* __restrict__ bhh0,
    const float* __restrict__ wih1,
    const float* __restrict__ whh1,
    const float* __restrict__ bih1,
    const float* __restrict__ bhh1,
    const float* __restrict__ w1,
    const float* __restrict__ b1,
    const float* __restrict__ w2,
    const float* __restrict__ b2,
    float* __restrict__ out)
{
    // h(t) lives in buffer t&1. Rows 8..15 stay zero (MFMA M=16 padding).
    __shared__ __align__(16) unsigned short h0b[2][16][HP];
    __shared__ __align__(16) unsigned short h1b[2][16][HP];
    __shared__ __align__(16) float b0t[HH][4];          // scaled bias0 [col][g]
    __shared__ __align__(16) float b1t[HH][4];          // scaled bias1 [col][g]
    __shared__ __align__(16) float wab[HH][8];          // scaled wih0 [col][{wa,wb}x4g]
    __shared__ float hid[BB][FFD];

    const int tid  = threadIdx.x;
    const int lane = tid & 63;
    const int wv   = tid >> 6;        // 0..3
    const int nrow = lane & 15;       // MFMA m (A) / n (B) index
    const int kg   = lane >> 4;       // MFMA k-group 0..3
    const int lx   = lane ^ 32;       // cross-half partner for __shfl
    const int b0   = blockIdx.x * BB;

    // ---- init LDS ----
    {
        unsigned short* p0 = &h0b[0][0][0];
        unsigned short* p1 = &h1b[0][0][0];
        for (int i = tid; i < 2 * 16 * HP; i += NT) { p0[i] = 0; p1[i] = 0; }
        for (int i = tid; i < 4 * HH; i += NT) {      // i = 128g + col
            int g  = i >> 7;
            int jc = i & (HH - 1);
            float s = (g == 2) ? L2E2 : L2E;
            b0t[jc][g] = (bih0[i] + bhh0[i]) * s;
            b1t[jc][g] = (bih1[i] + bhh1[i]) * s;
            wab[jc][2 * g]     = wih0[2 * i] * s;
            wab[jc][2 * g + 1] = wih0[2 * i + 1] * s;
        }
    }

    // ---- resident weight frags: 96 frags = 384 AGPR. t = g*2+h2 ----
    // B-frag 16x16x32: lane(n=lane&15, q=lane>>4) holds B[k=32kt+8q+e][n]=W[col][k]
    short8 W0[8][4], Wi[8][4], Wh[8][4];
#pragma unroll
    for (int g = 0; g < 4; g++)
#pragma unroll
        for (int h2 = 0; h2 < 2; h2++) {
            const float s = (g == 2) ? L2E2 : L2E;
            const int t = g * 2 + h2;
            unsigned gc = (unsigned)(128 * g + 32 * wv + 16 * h2 + nrow);
#pragma unroll
            for (int kt = 0; kt < 4; kt++) {
                unsigned off = gc * HH + kt * 32 + kg * 8;
                W0[t][kt] = ldfrag(whh0, off, s);
                asm volatile("" : "+a"(W0[t][kt]));
            }
#pragma unroll
            for (int kt = 0; kt < 4; kt++) {
                unsigned off = gc * HH + kt * 32 + kg * 8;
                Wi[t][kt] = ldfrag(wih1, off, s);
                asm volatile("" : "+a"(Wi[t][kt]));
            }
#pragma unroll
            for (int kt = 0; kt < 4; kt++) {
                unsigned off = gc * HH + kt * 32 + kg * 8;
                Wh[t][kt] = ldfrag(whh1, off, s);
                asm volatile("" : "+a"(Wh[t][kt]));
            }
        }

    const int j0    = 32 * wv + nrow;       // first owned col; second = j0+16
    const int rbase = (kg & 1) * 4 + (kg & 2);   // rows {rbase, rbase+1}
    float c0[2][2] = {{0.f, 0.f}, {0.f, 0.f}};   // [h2][u]
    float c1[2][2] = {{0.f, 0.f}, {0.f, 0.f}};
    __syncthreads();

    // ---- recurrence: ONE barrier per iteration ----
    for (int it = 0; it <= TT; it++) {
        const int p = (it + 1) & 1;   // buffer holding h0(it-1)
        const int q = it & 1;         // buffer for h0(it); holds h1(it-2)
        const bool doA = (it < TT);
        const bool doB = (it > 0);

        // x for cell0 (rows rbase, rbase+1) — issued early, L1-resident
        float xh[2], xg[2];
        if (doA) {
#pragma unroll
            for (int u = 0; u < 2; u++) {
                unsigned gi = (unsigned)(b0 + rbase + u) * TT + it;
                xh[u] = hr[gi];
                xg[u] = glu[gi];
            }
        }
        // A-frags of h0(it-1) — shared by MM0 and MM1p1
        short8 a0[4];
#pragma unroll
        for (int kt = 0; kt < 4; kt++)
            a0[kt] = *reinterpret_cast<const short8*>(&h0b[p][nrow][kt * 32 + kg * 8]);

        if (doA) {
            // MM0(it): gates0 = bias0 + h0(it-1) @ whh0^T   (8 indep chains)
            f32x4 acc[8];
            {
                f32x4 bv0 = *reinterpret_cast<const f32x4*>(&b0t[j0][0]);
                f32x4 bv1 = *reinterpret_cast<const f32x4*>(&b0t[j0 + 16][0]);
#pragma unroll
                for (int g = 0; g < 4; g++) {
                    float ba = bv0[g], bb = bv1[g];
                    f32x4 za = {ba, ba, ba, ba}; acc[2 * g]     = za;
                    f32x4 zb = {bb, bb, bb, bb}; acc[2 * g + 1] = zb;
                }
            }
#pragma unroll
            for (int kt = 0; kt < 4; kt++)
#pragma unroll
                for (int t = 0; t < 8; t++)
                    acc[t] = MFMA(a0[kt], W0[t][kt], acc[t]);
            // cell0: 2 cols x 2 rows per lane, all 64 lanes. Rows {2,3,6,7}
            // arrive via __shfl from partner lane (acc regs 2,3 of lane^32).
#pragma unroll
            for (int h2 = 0; h2 < 2; h2++) {
                const int jc = j0 + 16 * h2;
                f32x4 w01 = *reinterpret_cast<const f32x4*>(&wab[jc][0]); // wa0,wb0,wa1,wb1
                f32x4 w23 = *reinterpret_cast<const f32x4*>(&wab[jc][4]); // wa2,wb2,wa3,wb3
#pragma unroll
                for (int u = 0; u < 2; u++) {
                    float ri = __shfl(acc[0 + h2][2 + u], lx, 64);
                    float rf = __shfl(acc[2 + h2][2 + u], lx, 64);
                    float rg = __shfl(acc[4 + h2][2 + u], lx, 64);
                    float ro = __shfl(acc[6 + h2][2 + u], lx, 64);
                    float vi = (kg < 2) ? acc[0 + h2][u] : ri;
                    float vf = (kg < 2) ? acc[2 + h2][u] : rf;
                    float vg = (kg < 2) ? acc[4 + h2][u] : rg;
                    float vo = (kg < 2) ? acc[6 + h2][u] : ro;
                    float pi = vi + xh[u] * w01[0] + xg[u] * w01[1];
                    float pf = vf + xh[u] * w01[2] + xg[u] * w01[3];
                    float pg = vg + xh[u] * w23[0] + xg[u] * w23[1];
                    float po = vo + xh[u] * w23[2] + xg[u] * w23[3];
                    float ig = sigm_s(pi), fg = sigm_s(pf), gg = tanh_s(pg), og = sigm_s(po);
                    float c = fg * c0[h2][u] + ig * gg;
                    c0[h2][u] = c;
                    h0b[q][rbase + u][jc] = f2b(og * tanh_c(c));   // h0(it) -> buf q
                }
            }
        }
        if (doB) {
            // MM1(it-1): gates1 = bias1 + h0(it-1)@wih1^T + h1(it-2)@whh1^T
            f32x4 acc[8];
            {
                f32x4 bv0 = *reinterpret_cast<const f32x4*>(&b1t[j0][0]);
                f32x4 bv1 = *reinterpret_cast<const f32x4*>(&b1t[j0 + 16][0]);
#pragma unroll
                for (int g = 0; g < 4; g++) {
                    float ba = bv0[g], bb = bv1[g];
                    f32x4 za = {ba, ba, ba, ba}; acc[2 * g]     = za;
                    f32x4 zb = {bb, bb, bb, bb}; acc[2 * g + 1] = zb;
                }
            }
#pragma unroll
            for (int kt = 0; kt < 4; kt++)
#pragma unroll
                for (int t = 0; t < 8; t++)
                    acc[t] = MFMA(a0[kt], Wi[t][kt], acc[t]);
#pragma unroll
            for (int kt = 0; kt < 4; kt++) {
                short8 a1 = *reinterpret_cast<const short8*>(&h1b[q][nrow][kt * 32 + kg * 8]);
#pragma unroll
                for (int t = 0; t < 8; t++)
                    acc[t] = MFMA(a1, Wh[t][kt], acc[t]);
            }
            // cell1(it-1): pre-activation complete (bias folded); h1 -> buf p
#pragma unroll
            for (int h2 = 0; h2 < 2; h2++) {
                const int jc = j0 + 16 * h2;
#pragma unroll
                for (int u = 0; u < 2; u++) {
                    float ri = __shfl(acc[0 + h2][2 + u], lx, 64);
                    float rf = __shfl(acc[2 + h2][2 + u], lx, 64);
                    float rg = __shfl(acc[4 + h2][2 + u], lx, 64);
                    float ro = __shfl(acc[6 + h2][2 + u], lx, 64);
                    float pi = (kg < 2) ? acc[0 + h2][u] : ri;
                    float pf = (kg < 2) ? acc[2 + h2][u] : rf;
                    float pg = (kg < 2) ? acc[4 + h2][u] : rg;
                    float po = (kg < 2) ? acc[6 + h2][u] : ro;
                    float ig = sigm_s(pi), fg = sigm_s(pf), gg = tanh_s(pg), og = sigm_s(po);
                    float c = fg * c1[h2][u] + ig * gg;
                    c1[h2][u] = c;
                    h1b[p][rbase + u][jc] = f2b(og * tanh_c(c));
                }
            }
        }
        __syncthreads();
    }

    // ---- head: h1 final = h1(TT-1) in h1b[(TT+1)&1] = h1b[1] ----
    for (int idx = tid; idx < BB * FFD; idx += NT) {
        int r  = idx >> 6;
        int ff = idx & 63;
        float a2 = 0.f;
        for (int k = 0; k < HH; k++)
            a2 += b2f(h1b[1][r][k]) * w1[(unsigned)ff * HH + k];
        hid[r][ff] = fmaxf(a2 + b1[ff], 0.f);
    }
    __syncthreads();
    if (tid < 16) {
        int r = tid >> 1;
        int o = tid & 1;
        float a2 = b2[o];
        for (int k = 0; k < FFD; k++)
            a2 += hid[r][k] * w2[(unsigned)o * FFD + k];
        out[(b0 + r) * 2 + o] = a2;    // fp32 output
    }
}

extern "C" void kernel_launch(void* const* d_in, const int* in_sizes, int n_in,
                              void* d_out, int out_size, void* d_ws, size_t ws_size,
                              hipStream_t stream) {
    const float* hr   = (const float*)d_in[0];
    const float* glu  = (const float*)d_in[1];
    const float* wih0 = (const float*)d_in[2];
    const float* whh0 = (const float*)d_in[3];
    const float* bih0 = (const float*)d_in[4];
    const float* bhh0 = (const float*)d_in[5];
    const float* wih1 = (const float*)d_in[6];
    const float* whh1 = (const float*)d_in[7];
    const float* bih1 = (const float*)d_in[8];
    const float* bhh1 = (const float*)d_in[9];
    const float* w1   = (const float*)d_in[10];
    const float* b1   = (const float*)d_in[11];
    const float* w2   = (const float*)d_in[12];
    const float* b2   = (const float*)d_in[13];
    float* out = (float*)d_out;

    lstm2_fused<<<dim3(2048 / BB), dim3(NT), 0, stream>>>(
        hr, glu, wih0, whh0, bih0, bhh0, wih1, whh1, bih1, bhh1,
        w1, b1, w2, b2, out);
}